// Round 4
// baseline (215.076 us; speedup 1.0000x reference)
//
#include <hip/hip_runtime.h>
#include <hip/hip_bf16.h>
#include <math.h>

// Problem constants
#define SPAN 845            // 5 * 169 = 13*13*5 cells per channel span
#define PLANE 169           // 13*13
#define NCH3 63             // 21 joints * 3 coords
#define NCHIN 64            // 63 uvd channels + 1 conf channel
#define NUM_CLASS 45
#define NUM_SEG 5

typedef float floatx4 __attribute__((ext_vector_type(4)));  // native vec for NT builtins

__device__ __forceinline__ float sigmoidf_(float x) {
    return 1.0f / (1.0f + expf(-x));
}

// Kernel 1: permute + sigmoid(joint0 channels) + per-sample argmax of conf.
// Grid: bs*16 blocks. Block (b, g), 4 warps:
//   g 0..14 : warp w handles channel ch3 = 4g+w (permute+store)
//   g == 15 : warps 0..2 handle ch3 = 60..62; warp 3 does conf argmax
__global__ __launch_bounds__(256) void permute_argmax_kernel(
        const float* __restrict__ in,       // (bs*64, 845)
        float* __restrict__ uvd_out,        // (bs*63, 845)
        float* __restrict__ top_out)        // (bs,) float(index)
{
    const int blk  = blockIdx.x;
    const int b    = blk >> 4;
    const int g    = blk & 15;
    const int tid  = threadIdx.x;
    const int warp = tid >> 6;
    const int lane = tid & 63;

    __shared__ float lds[4 * SPAN];

    // Coalesced float4 streaming load of 4 contiguous channel spans
    // (base (b*64+4g)*845 floats is a multiple of 4 -> 16B aligned).
    const floatx4* in4 = (const floatx4*)in + (size_t)(b * 16 + g) * SPAN;
    floatx4* lds4 = (floatx4*)lds;
    for (int f = tid; f < SPAN; f += 256) {
        lds4[f] = __builtin_nontemporal_load(&in4[f]);
    }
    __syncthreads();

    if (g != 15 || warp != 3) {
        // Permute one channel per warp: out[t = ij*5+d] = src[d*169+ij].
        const int c   = warp;
        const int ch3 = g * 4 + c;
        const bool sig = (ch3 < 3);          // HAND_ROOT joint channels
        const float* src = lds + c * SPAN;
        float* dst = uvd_out + (size_t)(b * NCH3 + ch3) * SPAN;
        for (int t = lane; t < SPAN; t += 64) {
            const int ij = t / 5;
            const int d  = t - ij * 5;
            float v = src[d * PLANE + ij];
            if (sig) v = sigmoidf_(v);
            __builtin_nontemporal_store(v, &dst[t]);
        }
    } else {
        // Argmax over conf logits (sigmoid monotonic -> raw argmax).
        // Tie-break: lowest flat t (matches jax.lax.top_k stability).
        const float* conf = lds + 3 * SPAN;
        float bv = -INFINITY;
        int   bi = SPAN;
        for (int t = lane; t < SPAN; t += 64) {
            const int ij = t / 5;
            const int d  = t - ij * 5;
            const float v = conf[d * PLANE + ij];
            if (v > bv) { bv = v; bi = t; }  // t increasing -> keeps lowest t
        }
        for (int off = 32; off > 0; off >>= 1) {
            const float ov = __shfl_down(bv, off);
            const int   oi = __shfl_down(bi, off);
            if (ov > bv || (ov == bv && oi < bi)) { bv = ov; bi = oi; }
        }
        if (lane == 0) top_out[b] = (float)bi;
    }
}

// Kernel 2: per clip, gather best-cell uvd from the RAW input (recompute the
// joint-0 sigmoid), average over 5 segments, apply linear FC (mean commutes
// with the linear layer).
__global__ __launch_bounds__(64) void fc_consensus_kernel(
        const float* __restrict__ in,       // (bs*64, 845)
        const float* __restrict__ top_out,  // (bs,) float(index)
        const float* __restrict__ fc_w,     // (45, 63)
        const float* __restrict__ fc_b,     // (45,)
        float* __restrict__ out3)           // (bs/5, 45)
{
    const int clip = blockIdx.x;
    const int tid = threadIdx.x;
    __shared__ float avg[NCH3];

    if (tid < NCH3) {
        float s = 0.0f;
        for (int seg = 0; seg < NUM_SEG; ++seg) {
            const int b = clip * NUM_SEG + seg;
            const int t = (int)top_out[b];
            const int ij = t / 5;
            const int d  = t - ij * 5;
            float v = in[((size_t)b * NCHIN + tid) * SPAN + d * PLANE + ij];
            if (tid < 3) v = sigmoidf_(v);   // joint 0 sigmoid
            s += v;
        }
        avg[tid] = s * (1.0f / NUM_SEG);
    }
    __syncthreads();
    if (tid < NUM_CLASS) {
        float acc = fc_b[tid];
        #pragma unroll
        for (int k = 0; k < NCH3; ++k) acc += avg[k] * fc_w[tid * NCH3 + k];
        out3[clip * NUM_CLASS + tid] = acc;
    }
}

extern "C" void kernel_launch(void* const* d_in, const int* in_sizes, int n_in,
                              void* d_out, int out_size, void* d_ws, size_t ws_size,
                              hipStream_t stream) {
    const float* base_out = (const float*)d_in[0];
    const float* fc_w     = (const float*)d_in[1];
    const float* fc_b     = (const float*)d_in[2];

    const int bs = in_sizes[0] / (NCHIN * SPAN);   // 2560
    const int clips = bs / NUM_SEG;                // 512

    float* uvd_out = (float*)d_out;                        // bs*63*845
    float* top_out = uvd_out + (size_t)bs * NCH3 * SPAN;   // bs
    float* out3    = top_out + bs;                         // clips*45

    permute_argmax_kernel<<<bs * 16, 256, 0, stream>>>(base_out, uvd_out, top_out);
    fc_consensus_kernel<<<clips, 64, 0, stream>>>(base_out, top_out, fc_w, fc_b, out3);
}

// Round 5
// 206.028 us; speedup vs baseline: 1.0439x; 1.0439x over previous
//
#include <hip/hip_runtime.h>
#include <hip/hip_bf16.h>
#include <math.h>

// Problem constants
#define SPAN 845            // 5 * 169 = 13*13*5 cells per channel span
#define PLANE 169           // 13*13
#define NCH3 63             // 21 joints * 3 coords
#define NCHIN 64            // 63 uvd channels + 1 conf channel
#define NUM_CLASS 45
#define NUM_SEG 5

__device__ __forceinline__ float sigmoidf_(float x) {
    return 1.0f / (1.0f + expf(-x));
}

// Kernel 1: permute + sigmoid(joint0 channels) + per-sample argmax of conf.
// Grid: bs*16 blocks. Block (b, g), 4 warps:
//   g 0..14 : warp w handles channel ch3 = 4g+w (permute+store)
//   g == 15 : warps 0..2 handle ch3 = 60..62; warp 3 does conf argmax
// Plain cached loads/stores (NT bypass measured -9 us in R3: L2 merging of
// the 4B-aligned channel-span boundaries helps the store stream).
__global__ __launch_bounds__(256) void permute_argmax_kernel(
        const float* __restrict__ in,       // (bs*64, 845)
        float* __restrict__ uvd_out,        // (bs*63, 845)
        float* __restrict__ top_out)        // (bs,) float(index)
{
    const int blk  = blockIdx.x;
    const int b    = blk >> 4;
    const int g    = blk & 15;
    const int tid  = threadIdx.x;
    const int warp = tid >> 6;
    const int lane = tid & 63;

    __shared__ float lds[4 * SPAN];

    // Coalesced float4 load of 4 contiguous channel spans
    // (base (b*64+4g)*845 floats is a multiple of 4 -> 16B aligned).
    const float4* in4 = (const float4*)in + (size_t)(b * 16 + g) * SPAN;
    float4* lds4 = (float4*)lds;
    for (int f = tid; f < SPAN; f += 256) {
        lds4[f] = in4[f];
    }
    __syncthreads();

    if (g != 15 || warp != 3) {
        // Permute one channel per warp: out[t = ij*5+d] = src[d*169+ij].
        // LDS read banks: addr = d*169+ij, 169 mod 32 = 9 -> spread, ~2-way.
        const int c   = warp;
        const int ch3 = g * 4 + c;
        const bool sig = (ch3 < 3);          // HAND_ROOT joint channels
        const float* src = lds + c * SPAN;
        float* dst = uvd_out + (size_t)(b * NCH3 + ch3) * SPAN;
        for (int t = lane; t < SPAN; t += 64) {
            const int ij = t / 5;
            const int d  = t - ij * 5;
            float v = src[d * PLANE + ij];
            if (sig) v = sigmoidf_(v);
            dst[t] = v;
        }
    } else {
        // Argmax over conf logits (sigmoid monotonic -> raw argmax).
        // Tie-break: lowest flat t (matches jax.lax.top_k stability).
        const float* conf = lds + 3 * SPAN;
        float bv = -INFINITY;
        int   bi = SPAN;
        for (int t = lane; t < SPAN; t += 64) {
            const int ij = t / 5;
            const int d  = t - ij * 5;
            const float v = conf[d * PLANE + ij];
            if (v > bv) { bv = v; bi = t; }  // t increasing -> keeps lowest t
        }
        for (int off = 32; off > 0; off >>= 1) {
            const float ov = __shfl_down(bv, off);
            const int   oi = __shfl_down(bi, off);
            if (ov > bv || (ov == bv && oi < bi)) { bv = ov; bi = oi; }
        }
        if (lane == 0) top_out[b] = (float)bi;
    }
}

// Kernel 2: per clip, gather best-cell uvd from the RAW input (recompute the
// joint-0 sigmoid), average over 5 segments, apply linear FC (mean commutes
// with the linear layer).
__global__ __launch_bounds__(64) void fc_consensus_kernel(
        const float* __restrict__ in,       // (bs*64, 845)
        const float* __restrict__ top_out,  // (bs,) float(index)
        const float* __restrict__ fc_w,     // (45, 63)
        const float* __restrict__ fc_b,     // (45,)
        float* __restrict__ out3)           // (bs/5, 45)
{
    const int clip = blockIdx.x;
    const int tid = threadIdx.x;
    __shared__ float avg[NCH3];

    if (tid < NCH3) {
        float s = 0.0f;
        for (int seg = 0; seg < NUM_SEG; ++seg) {
            const int b = clip * NUM_SEG + seg;
            const int t = (int)top_out[b];
            const int ij = t / 5;
            const int d  = t - ij * 5;
            float v = in[((size_t)b * NCHIN + tid) * SPAN + d * PLANE + ij];
            if (tid < 3) v = sigmoidf_(v);   // joint 0 sigmoid
            s += v;
        }
        avg[tid] = s * (1.0f / NUM_SEG);
    }
    __syncthreads();
    if (tid < NUM_CLASS) {
        float acc = fc_b[tid];
        #pragma unroll
        for (int k = 0; k < NCH3; ++k) acc += avg[k] * fc_w[tid * NCH3 + k];
        out3[clip * NUM_CLASS + tid] = acc;
    }
}

extern "C" void kernel_launch(void* const* d_in, const int* in_sizes, int n_in,
                              void* d_out, int out_size, void* d_ws, size_t ws_size,
                              hipStream_t stream) {
    const float* base_out = (const float*)d_in[0];
    const float* fc_w     = (const float*)d_in[1];
    const float* fc_b     = (const float*)d_in[2];

    const int bs = in_sizes[0] / (NCHIN * SPAN);   // 2560
    const int clips = bs / NUM_SEG;                // 512

    float* uvd_out = (float*)d_out;                        // bs*63*845
    float* top_out = uvd_out + (size_t)bs * NCH3 * SPAN;   // bs
    float* out3    = top_out + bs;                         // clips*45

    permute_argmax_kernel<<<bs * 16, 256, 0, stream>>>(base_out, uvd_out, top_out);
    fc_consensus_kernel<<<clips, 64, 0, stream>>>(base_out, top_out, fc_w, fc_b, out3);
}